// Round 2
// baseline (639.703 us; speedup 1.0000x reference)
//
#include <hip/hip_runtime.h>
#include <hip/hip_bf16.h>

// ---------------- problem constants ----------------
#define BATCH 16
#define CI    512
#define CO    512
#define IMG   64      // H = W
#define HP    66      // padded H/W
#define NPIX  4096    // IMG*IMG
#define NTAP  9

typedef __bf16  bf16x8  __attribute__((ext_vector_type(8)));
typedef float   floatx4 __attribute__((ext_vector_type(4)));

// ---------------- workspace layout (bytes) ----------------
#define OFF_S     0u
#define OFF_SIG   32768u
#define OFF_WSQ   65536u
#define OFF_WBF   1114112u
#define OFF_XPAD  5832704u
#define XPAD_BYTES 71368704u
#define WS_NEEDED (OFF_XPAD + XPAD_BYTES)

// ---------------- prep: s = style @ (affine_w/sqrt(512)).T + affine_b ----------------
__global__ void k_style(const float* __restrict__ style, const float* __restrict__ aw,
                        const float* __restrict__ ab, float* __restrict__ s_out)
{
    __shared__ float st[512];
    int b = blockIdx.x;
    int t = threadIdx.x;
    st[t]       = style[b * 512 + t];
    st[t + 256] = style[b * 512 + t + 256];
    __syncthreads();
    int i = blockIdx.y * 256 + t;
    const float4* awr = (const float4*)(aw + (size_t)i * 512);
    float sum = 0.f;
#pragma unroll 8
    for (int k = 0; k < 128; ++k) {
        float4 v = awr[k];
        sum += v.x * st[4 * k] + v.y * st[4 * k + 1] + v.z * st[4 * k + 2] + v.w * st[4 * k + 3];
    }
    s_out[b * 512 + i] = sum * 0.04419417382415922f + ab[i];
}

// ---------------- prep: wsq[o,i] = sum_t w^2, wbf[tap][o][ci] = bf16(w) ----------------
__global__ void k_wprep(const float* __restrict__ wgt, float* __restrict__ wsq,
                        unsigned short* __restrict__ wbf)
{
    int idx = blockIdx.x * 256 + threadIdx.x;   // 0 .. 262143 == o*512+ci
    const float* p = wgt + (size_t)idx * 9;
    float q = 0.f;
#pragma unroll
    for (int t9 = 0; t9 < 9; ++t9) {
        float v = p[t9];
        q += v * v;
        __hip_bfloat16 hv = __float2bfloat16(v);
        wbf[t9 * 262144 + idx] = *(unsigned short*)&hv;
    }
    wsq[idx] = q;
}

// ---------------- prep: sigma_inv[b,o] = rsqrt(sum_i wsq[o,i]*s[b,i]^2 + eps) ----------------
__global__ void k_sigma(const float* __restrict__ s_in, const float* __restrict__ wsq,
                        float* __restrict__ sig)
{
    __shared__ float s2[512];
    int b = blockIdx.x, t = threadIdx.x;
    float a0 = s_in[b * 512 + t], a1 = s_in[b * 512 + t + 256];
    s2[t] = a0 * a0;
    s2[t + 256] = a1 * a1;
    __syncthreads();
    int o = blockIdx.y * 256 + t;
    const float4* wr = (const float4*)(wsq + (size_t)o * 512);
    float sum = 0.f;
#pragma unroll 8
    for (int k = 0; k < 128; ++k) {
        float4 v = wr[k];
        sum += v.x * s2[4 * k] + v.y * s2[4 * k + 1] + v.z * s2[4 * k + 2] + v.w * s2[4 * k + 3];
    }
    sig[b * 512 + o] = rsqrtf(sum + 1e-8f);
}

// ---------------- prep: zero only the halo ring of xpad (replaces 71 MB memset) ----------
__global__ void k_halo(unsigned short* __restrict__ xpad)
{
    int b = blockIdx.x, p = blockIdx.y, t = threadIdx.x;
    int h, w;
    if (p < 66)       { h = 0;            w = p; }
    else if (p < 132) { h = 65;           w = p - 66; }
    else if (p < 196) { h = 1 + (p - 132); w = 0; }
    else              { h = 1 + (p - 196); w = 65; }
    unsigned int* dst = (unsigned int*)(xpad + ((size_t)((b * 66 + h) * 66 + w)) * 512);
    dst[t] = 0u;
}

// ---------------- prep: xpad[b][h+1][w+1][ci] = bf16(x * s), NHWC, vectorized ----------
// LDS tile: 64 w x 256 ci bf16 with 16B-chunk XOR swizzle:
//   element (w, ci) lives at shorts offset w*256 + ((ci>>3) ^ ((w>>2)&7))*8 + (ci&7)
__global__ void k_xmod(const float* __restrict__ x, const float* __restrict__ s_in,
                       unsigned short* __restrict__ xpad)
{
    __shared__ unsigned short tile[64 * 256];
    __shared__ float sm_s[256];
    int b = blockIdx.x, h = blockIdx.y, half = blockIdx.z;
    int ci0 = half * 256;
    int t = threadIdx.x;

    sm_s[t] = s_in[b * 512 + ci0 + t];
    __syncthreads();

    int w0 = (t & 15) * 4;
    int cp = (t >> 4) * 2;     // ci pair base within 32-ci group
#pragma unroll
    for (int i = 0; i < 8; ++i) {
        int ci_l = i * 32 + cp;
        float sv0 = sm_s[ci_l], sv1 = sm_s[ci_l + 1];
        const float4 v0 = *(const float4*)(x + (((size_t)(b * 512 + ci0 + ci_l)) << 12) + (h << 6) + w0);
        const float4 v1 = *(const float4*)(x + (((size_t)(b * 512 + ci0 + ci_l + 1)) << 12) + (h << 6) + w0);
        float a0[4] = {v0.x, v0.y, v0.z, v0.w};
        float a1[4] = {v1.x, v1.y, v1.z, v1.w};
#pragma unroll
        for (int j = 0; j < 4; ++j) {
            int w = w0 + j;
            __hip_bfloat16 h0 = __float2bfloat16(a0[j] * sv0);
            __hip_bfloat16 h1 = __float2bfloat16(a1[j] * sv1);
            unsigned int packed = (unsigned int)(*(unsigned short*)&h0)
                                | ((unsigned int)(*(unsigned short*)&h1) << 16);
            int off = w * 256 + (((ci_l >> 3) ^ ((w >> 2) & 7)) << 3) + (ci_l & 7);
            *(unsigned int*)&tile[off] = packed;
        }
    }
    __syncthreads();

    // write out: per iteration 8 w-rows; lane covers 8 ci (16 B)
    int q = t & 31;
#pragma unroll
    for (int i = 0; i < 8; ++i) {
        int w = i * 8 + (t >> 5);
        int off = w * 256 + ((q ^ ((w >> 2) & 7)) << 3);
        uint4 v = *(const uint4*)&tile[off];
        *(uint4*)(xpad + ((size_t)((b * 66 + h + 1) * 66 + (w + 1))) * 512 + ci0 + q * 8) = v;
    }
}

// ---------------- main conv: implicit GEMM, 128x128 tile, bank-swizzled LDS ----------
__device__ __forceinline__ void gload16(const void* g, void* l)
{
    __builtin_amdgcn_global_load_lds(
        (const __attribute__((address_space(1))) unsigned int*)g,
        (__attribute__((address_space(3))) unsigned int*)l, 16, 0, 0);
}

__global__ __launch_bounds__(256, 2)
void k_conv(const unsigned short* __restrict__ xpad, const unsigned short* __restrict__ wbf,
            const float* __restrict__ sig, float* __restrict__ y)
{
    // LDS slot (row r, chunk c_slot) holds global 16B-chunk c_slot ^ ((r>>1)&3)
    __shared__ unsigned short A_lds[4096];  // [128 o][32 k] bf16, 8 KB
    __shared__ unsigned short B_lds[4096];  // [128 pix][32 k] bf16, 8 KB
    int t = threadIdx.x;
    int w = t >> 6, l = t & 63;
    int wr = w >> 1, wc = w & 1;
    int bx = blockIdx.x;
    int b = bx >> 7, rem = bx & 127;
    int co_t = rem >> 5, pix_t = rem & 31;
    int o_base = co_t << 7;
    int h0 = pix_t << 1;

    const char* wb = (const char*)wbf;
    const char* xb = (const char*)xpad;

    int idx0 = (w << 6) + l;
    int idx1 = idx0 + 256;
    // staging swizzle: global chunk = (idx&3) ^ ((idx>>3)&3); identical for idx0/idx1
    int sw = (((idx0 & 3) ^ ((idx0 >> 3) & 3)) << 4);
    int aoff0 = ((o_base + (idx0 >> 2)) << 10) + sw;
    int aoff1 = ((o_base + (idx1 >> 2)) << 10) + sw;
    int p0 = idx0 >> 2, p1 = idx1 >> 2;
    int boff0 = (((b * 66 + h0 + (p0 >> 6)) * 66 + (p0 & 63)) << 10) + sw;
    int boff1 = (((b * 66 + h0 + (p1 >> 6)) * 66 + (p1 & 63)) << 10) + sw;
    char* aL0 = (char*)A_lds + (w << 10);
    char* aL1 = (char*)A_lds + 4096 + (w << 10);
    char* bL0 = (char*)B_lds + (w << 10);
    char* bL1 = (char*)B_lds + 4096 + (w << 10);

    floatx4 acc[4][4];
#pragma unroll
    for (int i = 0; i < 4; ++i)
#pragma unroll
        for (int j = 0; j < 4; ++j)
            acc[i][j] = (floatx4){0.f, 0.f, 0.f, 0.f};

    // fragment read offsets (shorts): row lr, want global chunk q=l>>4 -> slot q ^ ((lr>>1)&3)
    int lr = l & 15;
    int fsw = (((l >> 4) ^ ((lr >> 1) & 3)) << 3);
    int fa = wr * 2048 + lr * 32 + fsw;
    int fb = wc * 2048 + lr * 32 + fsw;

    for (int tap = 0; tap < 9; ++tap) {
        int kh = tap / 3;
        int kw = tap - kh * 3;
        int tb = (kh * 66 + kw) << 10;
        int ta = tap << 19;
        for (int cic = 0; cic < 16; ++cic) {
            int kb = cic << 6;
            gload16(wb + ta + kb + aoff0, aL0);
            gload16(wb + ta + kb + aoff1, aL1);
            gload16(xb + tb + kb + boff0, bL0);
            gload16(xb + tb + kb + boff1, bL1);
            __syncthreads();

            bf16x8 af[4], bfr[4];
#pragma unroll
            for (int i = 0; i < 4; ++i) af[i]  = *(const bf16x8*)&A_lds[fa + i * 512];
#pragma unroll
            for (int j = 0; j < 4; ++j) bfr[j] = *(const bf16x8*)&B_lds[fb + j * 512];
#pragma unroll
            for (int i = 0; i < 4; ++i)
#pragma unroll
                for (int j = 0; j < 4; ++j)
                    acc[i][j] = __builtin_amdgcn_mfma_f32_16x16x32_bf16(af[i], bfr[j], acc[i][j], 0, 0, 0);
            __syncthreads();
        }
    }

    // epilogue: C/D layout col=lane&15, row=quad*4+reg
    int col = l & 15, quad = l >> 4;
    const float* sb = sig + b * 512;
#pragma unroll
    for (int i = 0; i < 4; ++i) {
        int ob = o_base + wr * 64 + i * 16 + quad * 4;
#pragma unroll
        for (int r = 0; r < 4; ++r) {
            int o = ob + r;
            float sv = sb[o];
            float* yrow = y + (((size_t)(b * 512 + o)) << 12);
#pragma unroll
            for (int j = 0; j < 4; ++j) {
                int pix = (pix_t << 7) + wc * 64 + j * 16 + col;
                yrow[pix] = acc[i][j][r] * sv;
            }
        }
    }
}

// ---------------- launcher ----------------
extern "C" void kernel_launch(void* const* d_in, const int* in_sizes, int n_in,
                              void* d_out, int out_size, void* d_ws, size_t ws_size,
                              hipStream_t stream)
{
    const float* x        = (const float*)d_in[0];
    const float* style    = (const float*)d_in[1];
    const float* weight   = (const float*)d_in[2];
    const float* affine_w = (const float*)d_in[3];
    const float* affine_b = (const float*)d_in[4];
    float* y = (float*)d_out;

    if (ws_size < (size_t)WS_NEEDED) return;

    char* ws = (char*)d_ws;
    float*          s_buf = (float*)(ws + OFF_S);
    float*          sig   = (float*)(ws + OFF_SIG);
    float*          wsq   = (float*)(ws + OFF_WSQ);
    unsigned short* wbf   = (unsigned short*)(ws + OFF_WBF);
    unsigned short* xpad  = (unsigned short*)(ws + OFF_XPAD);

    k_halo<<<dim3(16, 260), 256, 0, stream>>>(xpad);
    k_style<<<dim3(16, 2), 256, 0, stream>>>(style, affine_w, affine_b, s_buf);
    k_wprep<<<1024, 256, 0, stream>>>(weight, wsq, wbf);
    k_sigma<<<dim3(16, 2), 256, 0, stream>>>(s_buf, wsq, sig);
    k_xmod<<<dim3(16, 64, 2), 256, 0, stream>>>(x, s_buf, xpad);
    k_conv<<<2048, 256, 0, stream>>>(xpad, wbf, sig, y);
}

// Round 3
// 560.336 us; speedup vs baseline: 1.1416x; 1.1416x over previous
//
#include <hip/hip_runtime.h>
#include <hip/hip_bf16.h>

// ---------------- problem constants ----------------
#define BATCH 16
#define CI    512
#define CO    512
#define IMG   64
#define HP    66
#define NPIX  4096
#define NTAP  9

typedef __bf16  bf16x8  __attribute__((ext_vector_type(8)));
typedef float   floatx4 __attribute__((ext_vector_type(4)));

// ---------------- workspace layout (bytes) ----------------
#define OFF_S     0u
#define OFF_SIG   32768u
#define OFF_WSQ   65536u
#define OFF_WBF   1114112u
#define OFF_XPAD  5832704u
#define XPAD_BYTES 71368704u
#define WS_NEEDED (OFF_XPAD + XPAD_BYTES)

// ---------------- prep: s = style @ (affine_w/sqrt(512)).T + affine_b ----------------
__global__ void k_style(const float* __restrict__ style, const float* __restrict__ aw,
                        const float* __restrict__ ab, float* __restrict__ s_out)
{
    __shared__ float st[512];
    int b = blockIdx.x;
    int t = threadIdx.x;
    st[t]       = style[b * 512 + t];
    st[t + 256] = style[b * 512 + t + 256];
    __syncthreads();
    int i = blockIdx.y * 256 + t;
    const float4* awr = (const float4*)(aw + (size_t)i * 512);
    float sum = 0.f;
#pragma unroll 8
    for (int k = 0; k < 128; ++k) {
        float4 v = awr[k];
        sum += v.x * st[4 * k] + v.y * st[4 * k + 1] + v.z * st[4 * k + 2] + v.w * st[4 * k + 3];
    }
    s_out[b * 512 + i] = sum * 0.04419417382415922f + ab[i];
}

// ---------------- prep: wsq[o,i] = sum_t w^2, wbf[tap][o][ci] = bf16(w) ----------------
__global__ void k_wprep(const float* __restrict__ wgt, float* __restrict__ wsq,
                        unsigned short* __restrict__ wbf)
{
    int idx = blockIdx.x * 256 + threadIdx.x;
    const float* p = wgt + (size_t)idx * 9;
    float q = 0.f;
#pragma unroll
    for (int t9 = 0; t9 < 9; ++t9) {
        float v = p[t9];
        q += v * v;
        __hip_bfloat16 hv = __float2bfloat16(v);
        wbf[t9 * 262144 + idx] = *(unsigned short*)&hv;
    }
    wsq[idx] = q;
}

// ---------------- prep: sigma_inv[b,o] = rsqrt(sum_i wsq[o,i]*s[b,i]^2 + eps) ----------------
__global__ void k_sigma(const float* __restrict__ s_in, const float* __restrict__ wsq,
                        float* __restrict__ sig)
{
    __shared__ float s2[512];
    int b = blockIdx.x, t = threadIdx.x;
    float a0 = s_in[b * 512 + t], a1 = s_in[b * 512 + t + 256];
    s2[t] = a0 * a0;
    s2[t + 256] = a1 * a1;
    __syncthreads();
    int o = blockIdx.y * 256 + t;
    const float4* wr = (const float4*)(wsq + (size_t)o * 512);
    float sum = 0.f;
#pragma unroll 8
    for (int k = 0; k < 128; ++k) {
        float4 v = wr[k];
        sum += v.x * s2[4 * k] + v.y * s2[4 * k + 1] + v.z * s2[4 * k + 2] + v.w * s2[4 * k + 3];
    }
    sig[b * 512 + o] = rsqrtf(sum + 1e-8f);
}

// ---------------- prep: xpad NHWC bf16 modulate + halo, 128-ci slices ----------------
__global__ void k_xmod(const float* __restrict__ x, const float* __restrict__ s_in,
                       unsigned short* __restrict__ xpad)
{
    __shared__ unsigned short tile[64 * 128];   // 16 KB
    __shared__ float sm_s[128];
    int b = blockIdx.x, h = blockIdx.y, quarter = blockIdx.z;
    int ci0 = quarter << 7;
    int t = threadIdx.x;
    if (t < 128) sm_s[t] = s_in[b * 512 + ci0 + t];
    __syncthreads();

    int w0 = (t & 15) << 2;
    int cp = (t >> 4) << 1;
#pragma unroll
    for (int i = 0; i < 4; ++i) {
        int cl = (i << 5) + cp;
        float sv0 = sm_s[cl], sv1 = sm_s[cl + 1];
        float4 v0 = *(const float4*)(x + (((size_t)(b * 512 + ci0 + cl)) << 12) + (h << 6) + w0);
        float4 v1 = *(const float4*)(x + (((size_t)(b * 512 + ci0 + cl + 1)) << 12) + (h << 6) + w0);
        float a0[4] = {v0.x, v0.y, v0.z, v0.w};
        float a1[4] = {v1.x, v1.y, v1.z, v1.w};
#pragma unroll
        for (int j = 0; j < 4; ++j) {
            int wq = w0 + j;
            __hip_bfloat16 h0 = __float2bfloat16(a0[j] * sv0);
            __hip_bfloat16 h1 = __float2bfloat16(a1[j] * sv1);
            unsigned int packed = (unsigned int)(*(unsigned short*)&h0)
                                | ((unsigned int)(*(unsigned short*)&h1) << 16);
            int off = (wq << 7) + ((((cl >> 3) ^ ((wq >> 2) & 7))) << 3) + (cl & 7);
            *(unsigned int*)&tile[off] = packed;
        }
    }
    __syncthreads();

    int q = t & 15;
    size_t rowb = (size_t)((b * 66 + h + 1) * 66 + 1) * 512 + ci0;
#pragma unroll
    for (int i = 0; i < 4; ++i) {
        int wq = (i << 4) + (t >> 4);
        int off = (wq << 7) + ((q ^ ((wq >> 2) & 7)) << 3);
        uint4 v = *(const uint4*)&tile[off];
        *(uint4*)(xpad + rowb + (size_t)wq * 512 + (q << 3)) = v;
    }

    // halo: w=0 / w=65 of this padded row
    uint4 z = {0u, 0u, 0u, 0u};
    if (t < 32) {
        int wp = (t >> 4) * 65;
        *(uint4*)(xpad + (size_t)((b * 66 + h + 1) * 66 + wp) * 512 + ci0 + ((t & 15) << 3)) = z;
    }
    // halo: full padded top/bottom rows
    if (h == 0 || h == 63) {
        int hp = (h == 0) ? 0 : 65;
        size_t base = (size_t)(b * 66 + hp) * 66 * 512 + ci0;
        for (int idx = t; idx < 66 * 16; idx += 256) {
            int p = idx >> 4, c = idx & 15;
            *(uint4*)(xpad + base + (size_t)p * 512 + (c << 3)) = z;
        }
    }
}

// ---------------- main conv: kh-strip implicit GEMM, 48 MFMA per barrier pair ----------
__device__ __forceinline__ void gload16(const void* g, void* l)
{
    __builtin_amdgcn_global_load_lds(
        (const __attribute__((address_space(1))) unsigned int*)g,
        (__attribute__((address_space(3))) unsigned int*)l, 16, 0, 0);
}

__global__ __launch_bounds__(256, 2)
void k_conv(const unsigned short* __restrict__ xpad, const unsigned short* __restrict__ wbf,
            const float* __restrict__ sig, float* __restrict__ y)
{
    // A: 3 taps x [128 o][32 k] (swizzled), B: 132-row strip x [32 k] (swizzled)
    __shared__ unsigned short A_lds[3 * 4096];   // 24576 B
    __shared__ unsigned short B_lds[4224];       // 8448 B
    int t = threadIdx.x;
    int w = t >> 6, l = t & 63;
    int wr = w >> 1, wc = w & 1;
    int bx = blockIdx.x;
    int b = bx >> 7, rem = bx & 127;
    int co_t = rem >> 5, pix_t = rem & 31;
    int o_base = co_t << 7;
    int h0 = pix_t << 1;                         // padded row base for kh=0

    const char* wb = (const char*)wbf;
    const char* xb = (const char*)xpad;

    // ---- staging offsets (per-thread, loop-invariant) ----
    int idx0 = (w << 6) + l;
    int idx1 = idx0 + 256;
    int asw = (((idx0 & 3) ^ ((idx0 >> 3) & 3)) << 4);     // same for idx1
    int aof0 = ((o_base + (idx0 >> 2)) << 10) + asw;
    int aof1 = aof0 + 65536;                               // +64 rows * 1024 B

    int r0 = idx0 >> 2;                                    // 0..63  (sr=0)
    int bof0 = ((b * 66 + h0) * 66 + r0) * 1024 + (((idx0 & 3) ^ ((r0 >> 1) & 3)) << 4);
    int r1 = idx1 >> 2;                                    // 64..127
    int sr1 = (r1 >= 66) ? 1 : 0;
    int wp1 = r1 - 66 * sr1;
    int bof1 = ((b * 66 + h0 + sr1) * 66 + wp1) * 1024 + (((idx1 & 3) ^ ((r1 >> 1) & 3)) << 4);
    int idxt = 512 + (w << 2) + l;                         // tail (lanes l<4)
    int rt = 128 + w;                                      // sr=1, wp=62+w
    int boft = ((b * 66 + h0 + 1) * 66 + 62 + w) * 1024 + (((idxt & 3) ^ ((rt >> 1) & 3)) << 4);

    char* aldsb = (char*)A_lds;
    char* bldsb = (char*)B_lds;
    char* aL00 = aldsb + (w << 10);
    char* aL01 = aldsb + 4096 + (w << 10);
    char* aL10 = aldsb + 8192 + (w << 10);
    char* aL11 = aldsb + 12288 + (w << 10);
    char* aL20 = aldsb + 16384 + (w << 10);
    char* aL21 = aldsb + 20480 + (w << 10);
    char* bL0 = bldsb + (w << 10);
    char* bL1 = bldsb + 4096 + (w << 10);
    char* bLt = bldsb + ((512 + (w << 2)) << 4);

    // ---- fragment offsets (shorts, loop-invariant) ----
    int lr = l & 15, q = l >> 4;
    int fa = wr * 2048 + lr * 32 + ((q ^ ((lr >> 1) & 3)) << 3);
    int fbo[3][4];
#pragma unroll
    for (int kw = 0; kw < 3; ++kw)
#pragma unroll
        for (int j = 0; j < 4; ++j) {
            int sp = wc * 66 + j * 16 + lr + kw;
            fbo[kw][j] = sp * 32 + ((q ^ ((sp >> 1) & 3)) << 3);
        }

    floatx4 acc[4][4];
#pragma unroll
    for (int i = 0; i < 4; ++i)
#pragma unroll
        for (int j = 0; j < 4; ++j)
            acc[i][j] = (floatx4){0.f, 0.f, 0.f, 0.f};

    for (int kh = 0; kh < 3; ++kh) {
        const char* wkh = wb + kh * 1572864;       // kh * 3 taps * 512 KB
        const char* xkh = xb + kh * 67584;         // kh * 66 rows * 1 KB
        for (int cic = 0; cic < 16; ++cic) {
            int kb = cic << 6;
            const char* wk = wkh + kb;
            const char* xk = xkh + kb;
            gload16(wk + aof0,           aL00);
            gload16(wk + aof1,           aL01);
            gload16(wk + 524288 + aof0,  aL10);
            gload16(wk + 524288 + aof1,  aL11);
            gload16(wk + 1048576 + aof0, aL20);
            gload16(wk + 1048576 + aof1, aL21);
            gload16(xk + bof0, bL0);
            gload16(xk + bof1, bL1);
            if (l < 4) gload16(xk + boft, bLt);
            __syncthreads();

#pragma unroll
            for (int kw = 0; kw < 3; ++kw) {
                bf16x8 bfr[4], af[4];
#pragma unroll
                for (int j = 0; j < 4; ++j) bfr[j] = *(const bf16x8*)&B_lds[fbo[kw][j]];
#pragma unroll
                for (int i = 0; i < 4; ++i) af[i]  = *(const bf16x8*)&A_lds[kw * 4096 + fa + i * 512];
#pragma unroll
                for (int i = 0; i < 4; ++i)
#pragma unroll
                    for (int j = 0; j < 4; ++j)
                        acc[i][j] = __builtin_amdgcn_mfma_f32_16x16x32_bf16(af[i], bfr[j], acc[i][j], 0, 0, 0);
            }
            __syncthreads();
        }
    }

    // epilogue: C/D layout col=lane&15 (pixel), row=quad*4+reg (co)
    int col = l & 15, quad = l >> 4;
    const float* sb = sig + b * 512;
#pragma unroll
    for (int i = 0; i < 4; ++i) {
        int ob = o_base + wr * 64 + i * 16 + quad * 4;
#pragma unroll
        for (int r = 0; r < 4; ++r) {
            int o = ob + r;
            float sv = sb[o];
            float* yrow = y + (((size_t)(b * 512 + o)) << 12);
#pragma unroll
            for (int j = 0; j < 4; ++j) {
                int pix = (pix_t << 7) + wc * 64 + j * 16 + col;
                yrow[pix] = acc[i][j][r] * sv;
            }
        }
    }
}

// ---------------- launcher ----------------
extern "C" void kernel_launch(void* const* d_in, const int* in_sizes, int n_in,
                              void* d_out, int out_size, void* d_ws, size_t ws_size,
                              hipStream_t stream)
{
    const float* x        = (const float*)d_in[0];
    const float* style    = (const float*)d_in[1];
    const float* weight   = (const float*)d_in[2];
    const float* affine_w = (const float*)d_in[3];
    const float* affine_b = (const float*)d_in[4];
    float* y = (float*)d_out;

    if (ws_size < (size_t)WS_NEEDED) return;

    char* ws = (char*)d_ws;
    float*          s_buf = (float*)(ws + OFF_S);
    float*          sig   = (float*)(ws + OFF_SIG);
    float*          wsq   = (float*)(ws + OFF_WSQ);
    unsigned short* wbf   = (unsigned short*)(ws + OFF_WBF);
    unsigned short* xpad  = (unsigned short*)(ws + OFF_XPAD);

    k_style<<<dim3(16, 2), 256, 0, stream>>>(style, affine_w, affine_b, s_buf);
    k_wprep<<<1024, 256, 0, stream>>>(weight, wsq, wbf);
    k_xmod<<<dim3(16, 64, 4), 256, 0, stream>>>(x, s_buf, xpad);
    k_sigma<<<dim3(16, 2), 256, 0, stream>>>(s_buf, wsq, sig);
    k_conv<<<2048, 256, 0, stream>>>(xpad, wbf, sig, y);
}